// Round 15
// baseline (320.521 us; speedup 1.0000x reference)
//
#include <hip/hip_runtime.h>

typedef __attribute__((ext_vector_type(8))) short short8;
typedef __attribute__((ext_vector_type(4))) float f32x4;
typedef unsigned short u16;

#define NTOK 49
#define NBLK 4096
#define LOG2E 1.4426950408889634f

// LDS pool (u16 units), 64 KB -> target 2 blocks/CU
// XF: x frags [rt4][ks8][64][8] (32 KB). After barrier (b): per-wave 2048-u16 slice
//     (4 slots of 512) = q/k frag scratch (sequential), then y frags at slot h*4+it.
// VY: 32 slots x 512 u16 (32 KB): v^T frag f of head h at slot f*8+h; slots reused for P.
#define XF 0
#define VY 16384
#define POOLN 32768

// workspace byte offsets (same as R14)
#define WS_WQT 0          // u16 wqTf[48][8][64][8]    = 393216  (q ctgs pre-scaled by SCQ)
#define WS_WOT 393216     // u16 woTf[16][8][64][8]    = 131072
#define WS_BQS 524288     // float bqs[768] (q part x SCQ), pad to 4096
#define WS_BIAS 528384    // float biasf[8][16][64][4] = 131072   (x LOG2E)
#define WS_MKG 659456     // float mkg[64][16][64][4]  = 1048576  (x LOG2E)
#define WS_CMB 1708032    // float cmb[64][8][16][64][4] = 8388608 (biasf+mkg)
#define WS_NEED (WS_CMB + 8388608)

__device__ __forceinline__ u16 f2bf(float f) {
  unsigned u = __float_as_uint(f);
  return (u16)((u + 0x7fffu + ((u >> 16) & 1u)) >> 16);
}
__device__ __forceinline__ unsigned packbf(float a, float b) {
  unsigned r;
  asm("v_cvt_pk_bf16_f32 %0, %1, %2" : "=v"(r) : "v"(a), "v"(b));
  return r;
}

// ---------------- prep1 (R14-verified) ----------------
__global__ void prep_kernel(const float* __restrict__ w_qkv,
                            const float* __restrict__ w_out,
                            const float* __restrict__ rel,
                            const float* __restrict__ mask,
                            const float* __restrict__ b_qkv,
                            u16* __restrict__ wqTf,
                            u16* __restrict__ woTf,
                            float* __restrict__ bqs,
                            float* __restrict__ biasf,
                            float* __restrict__ mkg) {
  const float SCQ = 0.17677669529663687f * LOG2E;
  const int stride = gridDim.x * blockDim.x;
  const int gid = blockIdx.x * blockDim.x + threadIdx.x;
  for (int e = gid; e < 48 * 8 * 64 * 8; e += stride) {
    int eL = e & 7, ln = (e >> 3) & 63, ks = (e >> 9) & 7, ctg = e >> 12;
    int k = ks * 32 + (ln >> 4) * 8 + eL;
    int c = ctg * 16 + (ln & 15);
    float wv = w_qkv[k * 768 + c];
    if (ctg < 16) wv *= SCQ;
    wqTf[e] = f2bf(wv);
  }
  for (int e = gid; e < 16 * 8 * 64 * 8; e += stride) {
    int eL = e & 7, ln = (e >> 3) & 63, ks = (e >> 9) & 7, ctg = e >> 12;
    int k = ks * 32 + (ln >> 4) * 8 + eL;
    int c = ctg * 16 + (ln & 15);
    woTf[e] = f2bf(w_out[k * 256 + c]);
  }
  for (int e = gid; e < 768; e += stride)
    bqs[e] = b_qkv[e] * (e < 256 ? SCQ : 1.f);
  for (int e = gid; e < 8 * 16 * 64 * 4; e += stride) {
    int rg = e & 3, ln = (e >> 2) & 63, t = (e >> 8) & 15, hh = e >> 12;
    int i = (t >> 2) * 16 + (ln & 15);
    int j = (t & 3) * 16 + (ln >> 4) * 4 + rg;
    float v;
    if (j >= NTOK) v = -1e30f;
    else if (i >= NTOK) v = 0.f;
    else {
      int dh = i / 7 - j / 7 + 6;
      int dw = i % 7 - j % 7 + 6;
      v = rel[(dh * 13 + dw) * 8 + hh];
    }
    biasf[e] = v * LOG2E;
  }
  for (int e = gid; e < 64 * 16 * 64 * 4; e += stride) {
    int rg = e & 3, ln = (e >> 2) & 63, t = (e >> 8) & 15, wdw = e >> 12;
    int i = (t >> 2) * 16 + (ln & 15);
    int j = (t & 3) * 16 + (ln >> 4) * 4 + rg;
    mkg[e] = (i < NTOK && j < NTOK) ? mask[wdw * (NTOK * NTOK) + i * NTOK + j] * LOG2E : 0.f;
  }
}

// ---------------- prep2: cmb = biasf + mkg (R14-verified) ----------------
__global__ void prep2_kernel(const float* __restrict__ biasf,
                             const float* __restrict__ mkg,
                             float* __restrict__ cmb) {
  const int stride = gridDim.x * blockDim.x;
  for (int e = blockIdx.x * blockDim.x + threadIdx.x; e < 64 * 8 * 4096; e += stride) {
    int x = e & 4095, hh = (e >> 12) & 7, wdw = e >> 15;
    cmb[e] = biasf[hh * 4096 + x] + mkg[wdw * 4096 + x];
  }
}

// ---------------- fused window attention: 8 waves, wave = head, 64 KB, <=128 regs ----------------
__global__ void __launch_bounds__(512, 2) winattn_mfma(
    const float* __restrict__ x,
    const float* __restrict__ bqs,
    const float* __restrict__ b_out,
    const u16* __restrict__ wqTf,
    const u16* __restrict__ woTf,
    const float* __restrict__ biasf,
    const float* __restrict__ mkg,
    const float* __restrict__ cmb,
    float* __restrict__ out)
{
  __shared__ u16 pool[POOLN];
  const int b = blockIdx.x, tid = threadIdx.x;
  const int lane = tid & 63, lo = lane & 15, hi = lane >> 4;
  const int h = tid >> 6;                    // wave = head, 0..7
  const f32x4 zf = {0.f, 0.f, 0.f, 0.f};

  // ---- stage: x -> XF frag order (loops cover all elements with 512 threads) ----
  {
    const float4* xg = (const float4*)(x + (size_t)b * (NTOK * 256));
    for (int e = tid; e < 49 * 64; e += 512) {
      float4 v = xg[e];
      int r = e >> 6, c4 = (e & 63) << 2;
      int addr = (((r >> 4) * 8 + (c4 >> 5)) * 64 + ((c4 >> 3) & 3) * 16 + (r & 15)) * 8 + (c4 & 7);
      *(uint2*)&pool[XF + addr] = make_uint2(packbf(v.x, v.y), packbf(v.z, v.w));
    }
    for (int e = tid; e < 15 * 64; e += 512) {   // zero-pad tokens 49..63 (960 elems: loop!)
      int r = 49 + (e >> 6), c4 = (e & 63) << 2;
      int addr = (((r >> 4) * 8 + (c4 >> 5)) * 64 + ((c4 >> 3) & 3) * 16 + (r & 15)) * 8 + (c4 & 7);
      *(uint2*)&pool[XF + addr] = make_uint2(0u, 0u);
    }
  }
  __syncthreads();   // (a) xf ready

  // ---- phase 1: QKV for head h — 3 passes of 2 ctgs (acc peak 32); pq/pk in regs, v -> VY ----
  unsigned pq[2][4][2], pk[2][4][2];
  #pragma unroll
  for (int pass = 0; pass < 3; ++pass) {
    const int c0 = (pass == 0) ? 2 * h : (pass == 1 ? 16 + 2 * h : 32 + 2 * h);
    f32x4 acc[2][4];
    #pragma unroll
    for (int ct = 0; ct < 2; ++ct)
      #pragma unroll
      for (int rt = 0; rt < 4; ++rt) acc[ct][rt] = zf;
    #pragma unroll
    for (int ks = 0; ks < 8; ++ks) {
      short8 bx[4];
      #pragma unroll
      for (int rt = 0; rt < 4; ++rt)
        bx[rt] = *(const short8*)&pool[XF + ((rt * 8 + ks) * 64 + lane) * 8];
      short8 af0 = *(const short8*)&wqTf[((size_t)((c0 + 0) * 8 + ks) * 64 + lane) * 8];
      short8 af1 = *(const short8*)&wqTf[((size_t)((c0 + 1) * 8 + ks) * 64 + lane) * 8];
      if (pass < 2) {
        #pragma unroll
        for (int rt = 0; rt < 4; ++rt) {
          acc[0][rt] = __builtin_amdgcn_mfma_f32_16x16x32_bf16(af0, bx[rt], acc[0][rt], 0, 0, 0);
          acc[1][rt] = __builtin_amdgcn_mfma_f32_16x16x32_bf16(af1, bx[rt], acc[1][rt], 0, 0, 0);
        }
      } else {   // v: swapped operands -> token-major D (R10/R11/R12-verified)
        #pragma unroll
        for (int rt = 0; rt < 4; ++rt) {
          acc[0][rt] = __builtin_amdgcn_mfma_f32_16x16x32_bf16(bx[rt], af0, acc[0][rt], 0, 0, 0);
          acc[1][rt] = __builtin_amdgcn_mfma_f32_16x16x32_bf16(bx[rt], af1, acc[1][rt], 0, 0, 0);
        }
      }
    }
    if (pass < 2) {
      #pragma unroll
      for (int ct = 0; ct < 2; ++ct) {
        f32x4 bias = *(const f32x4*)(bqs + (c0 + ct) * 16 + hi * 4);
        #pragma unroll
        for (int rt = 0; rt < 4; ++rt) {
          f32x4 v = acc[ct][rt] + bias;
          if (pass == 0) { pq[ct][rt][0] = packbf(v[0], v[1]); pq[ct][rt][1] = packbf(v[2], v[3]); }
          else           { pk[ct][rt][0] = packbf(v[0], v[1]); pk[ct][rt][1] = packbf(v[2], v[3]); }
        }
      }
    } else {
      #pragma unroll
      for (int ct = 0; ct < 2; ++ct) {
        const float bv = bqs[(c0 + ct) * 16 + lo];
        #pragma unroll
        for (int rt = 0; rt < 4; ++rt) {
          f32x4 v = acc[ct][rt];
          float v0 = v[0] + bv, v1 = v[1] + bv, v2 = v[2] + bv, v3 = v[3] + bv;
          int f = ct * 2 + (rt >> 1);
          int hiR = (rt & 1) * 2 + (hi >> 1);
          int eb = (hi & 1) * 4;
          *(uint2*)&pool[VY + (f * 8 + h) * 512 + (hiR * 16 + lo) * 8 + eb] =
              make_uint2(packbf(v0, v1), packbf(v2, v3));
        }
      }
    }
  }
  __syncthreads();   // (b) all x reads done -> XF becomes per-wave scratch

  // ---- q/k -> frag layout via wave-local XF slice (sequential reuse, no barrier) ----
  short8 qa[4], ka[4];
  {
    u16* slice = pool + XF + h * 2048;
    #pragma unroll
    for (int ct = 0; ct < 2; ++ct)
      #pragma unroll
      for (int rt = 0; rt < 4; ++rt) {
        int hi2 = ct * 2 + (hi >> 1);
        int eb = (hi & 1) * 4;
        *(uint2*)&slice[(rt * 64 + hi2 * 16 + lo) * 8 + eb] =
            make_uint2(pq[ct][rt][0], pq[ct][rt][1]);
      }
    #pragma unroll
    for (int jt = 0; jt < 4; ++jt)
      qa[jt] = *(const short8*)&slice[(jt * 64 + lane) * 8];
    #pragma unroll
    for (int ct = 0; ct < 2; ++ct)
      #pragma unroll
      for (int rt = 0; rt < 4; ++rt) {
        int hi2 = ct * 2 + (hi >> 1);
        int eb = (hi & 1) * 4;
        *(uint2*)&slice[(rt * 64 + hi2 * 16 + lo) * 8 + eb] =
            make_uint2(pk[ct][rt][0], pk[ct][rt][1]);
      }
    #pragma unroll
    for (int it = 0; it < 4; ++it)
      ka[it] = *(const short8*)&slice[(it * 64 + lane) * 8];
  }

  // ---- phases 2-4 fused per i-tile: QK^T -> softmax -> P via dead VY -> PV -> y to own XF ----
  {
    short8 va[2][2];
    #pragma unroll
    for (int dblk = 0; dblk < 2; ++dblk)
      #pragma unroll
      for (int k2 = 0; k2 < 2; ++k2)
        va[dblk][k2] = *(const short8*)&pool[VY + ((dblk * 2 + k2) * 8 + h) * 512 + lane * 8];
    // VY slots of head h now dead -> P scratch (wave-local)
    const float* cb;
    const float* mb = nullptr;
    if (cmb) {
      cb = cmb + (((size_t)(b & 63) * 8 + h) << 12);
    } else {
      cb = biasf + h * 4096;
      mb = mkg + (size_t)(b & 63) * 4096;
    }
    #pragma unroll
    for (int it = 0; it < 4; ++it) {
      float rs = 0.f;
      #pragma unroll
      for (int jt = 0; jt < 4; ++jt) {
        f32x4 s = __builtin_amdgcn_mfma_f32_16x16x32_bf16(qa[jt], ka[it], zf, 0, 0, 0);
        const int t = it * 4 + jt;
        f32x4 c4 = *(const f32x4*)&cb[(t * 64 + lane) * 4];
        if (mb) {
          f32x4 m4 = *(const f32x4*)&mb[(t * 64 + lane) * 4];
          c4[0] += m4[0]; c4[1] += m4[1]; c4[2] += m4[2]; c4[3] += m4[3];
        }
        float p0 = exp2f(s[0] + c4[0]);
        float p1 = exp2f(s[1] + c4[1]);
        float p2 = exp2f(s[2] + c4[2]);
        float p3 = exp2f(s[3] + c4[3]);
        rs += (p0 + p1) + (p2 + p3);
        // P -> dead VY slot (R13-verified): j = jt*16+hi*4+rg, i = lo
        int k2 = jt >> 1;
        int hi2 = (jt & 1) * 2 + (hi >> 1);
        int eb = (hi & 1) * 4;
        *(uint2*)&pool[VY + (k2 * 8 + h) * 512 + (hi2 * 16 + lo) * 8 + eb] =
            make_uint2(packbf(p0, p1), packbf(p2, p3));
      }
      float r2 = rs + __shfl_xor(rs, 16);
      const float inv = 1.f / (r2 + __shfl_xor(r2, 32));
      f32x4 ya0 = zf, ya1 = zf;
      #pragma unroll
      for (int k2 = 0; k2 < 2; ++k2) {
        short8 pb = *(const short8*)&pool[VY + (k2 * 8 + h) * 512 + lane * 8];
        ya0 = __builtin_amdgcn_mfma_f32_16x16x32_bf16(va[0][k2], pb, ya0, 0, 0, 0);
        ya1 = __builtin_amdgcn_mfma_f32_16x16x32_bf16(va[1][k2], pb, ya1, 0, 0, 0);
      }
      // y frag (tokens it*16.., channels of head h) -> own XF slot h*4+it
      #pragma unroll
      for (int dblk = 0; dblk < 2; ++dblk) {
        f32x4 yy = dblk ? ya1 : ya0;
        int hi2 = dblk * 2 + (hi >> 1);
        int eb = (hi & 1) * 4;
        *(uint2*)&pool[XF + (h * 4 + it) * 512 + (hi2 * 16 + lo) * 8 + eb] =
            make_uint2(packbf(yy[0] * inv, yy[1] * inv), packbf(yy[2] * inv, yy[3] * inv));
      }
    }
  }
  __syncthreads();   // (c) all y frags visible

  // ---- phase 5: output projection, 2 ctgs per wave; y frag (rt, ks) at XF slot ks*4+rt ----
  {
    f32x4 pacc[2][4];
    #pragma unroll
    for (int ct = 0; ct < 2; ++ct)
      #pragma unroll
      for (int rt = 0; rt < 4; ++rt) pacc[ct][rt] = zf;
    #pragma unroll
    for (int ks = 0; ks < 8; ++ks) {
      short8 yb[4];
      #pragma unroll
      for (int rt = 0; rt < 4; ++rt)
        yb[rt] = *(const short8*)&pool[XF + (ks * 4 + rt) * 512 + lane * 8];
      #pragma unroll
      for (int ct = 0; ct < 2; ++ct) {
        short8 wf = *(const short8*)&woTf[((size_t)((h * 2 + ct) * 8 + ks) * 64 + lane) * 8];
        #pragma unroll
        for (int rt = 0; rt < 4; ++rt)
          pacc[ct][rt] = __builtin_amdgcn_mfma_f32_16x16x32_bf16(wf, yb[rt], pacc[ct][rt], 0, 0, 0);
      }
    }
    float* og = out + (size_t)b * (NTOK * 256);
    #pragma unroll
    for (int ct = 0; ct < 2; ++ct) {
      const int cb2 = (h * 2 + ct) * 16 + hi * 4;
      f32x4 bb = *(const f32x4*)(b_out + cb2);
      #pragma unroll
      for (int rt = 0; rt < 4; ++rt) {
        const int r = rt * 16 + lo;
        if (r < NTOK) {
          f32x4 vv = pacc[ct][rt] + bb;
          *(f32x4*)(og + (size_t)r * 256 + cb2) = vv;
        }
      }
    }
  }
}

extern "C" void kernel_launch(void* const* d_in, const int* in_sizes, int n_in,
                              void* d_out, int out_size, void* d_ws, size_t ws_size,
                              hipStream_t stream) {
  const float *x = nullptr, *mask = nullptr, *w_qkv = nullptr, *b_qkv = nullptr,
              *rel_t = nullptr, *w_out = nullptr, *b_out = nullptr;
  for (int i = 0; i < n_in; ++i) {
    const float* p = (const float*)d_in[i];
    switch (in_sizes[i]) {
      case 4096 * 49 * 256: x = p; break;
      case 64 * 49 * 49:    mask = p; break;
      case 256 * 768:       w_qkv = p; break;
      case 768:             b_qkv = p; break;
      case 169 * 8:         rel_t = p; break;
      case 256 * 256:       w_out = p; break;
      case 256:             b_out = p; break;
    }
  }
  char* wsb = (char*)d_ws;
  u16* wqTf    = (u16*)(wsb + WS_WQT);
  u16* woTf    = (u16*)(wsb + WS_WOT);
  float* bqs   = (float*)(wsb + WS_BQS);
  float* biasf = (float*)(wsb + WS_BIAS);
  float* mkg   = (float*)(wsb + WS_MKG);
  const bool fits = (ws_size >= (size_t)WS_NEED);
  float* cmb   = fits ? (float*)(wsb + WS_CMB) : nullptr;

  hipLaunchKernelGGL(prep_kernel, dim3(1024), dim3(256), 0, stream,
                     w_qkv, w_out, rel_t, mask, b_qkv, wqTf, woTf, bqs, biasf, mkg);
  if (fits) {
    hipLaunchKernelGGL(prep2_kernel, dim3(2048), dim3(256), 0, stream,
                       biasf, mkg, cmb);
  }
  hipLaunchKernelGGL(winattn_mfma, dim3(NBLK), dim3(512), 0, stream,
                     x, bqs, b_out, wqTf, woTf, biasf, mkg, cmb, (float*)d_out);
}

// Round 16
// 279.059 us; speedup vs baseline: 1.1486x; 1.1486x over previous
//
#include <hip/hip_runtime.h>

typedef __attribute__((ext_vector_type(8))) short short8;
typedef __attribute__((ext_vector_type(4))) float f32x4;
typedef unsigned short u16;

#define NTOK 49
#define NBLK 4096
#define LOG2E 1.4426950408889634f

// LDS pool (u16 units), 128 KB
#define XF  0       // x frags [rt4][ks8][64][8] linear; later y frags [it4][h8][64][8]
#define QKP 16384   // per head 4096 u16: q[4][64][8] | k[4][64][8]
#define VTF 49152   // 32 slots x 512 u16: v^T frag f of head h at slot f*8+h; dead slots = P scratch
#define POOLN 65536 // 131072 B

// workspace byte offsets
#define WS_WQT 0          // u16 wqTf[48][8][64][8]    = 393216  (q ctgs pre-scaled by SCQ)
#define WS_WOT 393216     // u16 woTf[16][8][64][8]    = 131072
#define WS_BQS 524288     // float bqs[768] (q part x SCQ), pad to 4096
#define WS_BIAS 528384    // float biasf[8][16][64][4] = 131072   (x LOG2E)
#define WS_MKG 659456     // float mkg[64][16][64][4]  = 1048576  (x LOG2E)
#define WS_CMB 1708032    // float cmb[64][8][16][64][4] = 8388608 (biasf+mkg)
#define WS_NEED (WS_CMB + 8388608)

__device__ __forceinline__ u16 f2bf(float f) {
  unsigned u = __float_as_uint(f);
  return (u16)((u + 0x7fffu + ((u >> 16) & 1u)) >> 16);
}
__device__ __forceinline__ unsigned packbf(float a, float b) {
  unsigned r;
  asm("v_cvt_pk_bf16_f32 %0, %1, %2" : "=v"(r) : "v"(a), "v"(b));
  return r;
}

// ---------------- prep1 (R14-verified) ----------------
__global__ void prep_kernel(const float* __restrict__ w_qkv,
                            const float* __restrict__ w_out,
                            const float* __restrict__ rel,
                            const float* __restrict__ mask,
                            const float* __restrict__ b_qkv,
                            u16* __restrict__ wqTf,
                            u16* __restrict__ woTf,
                            float* __restrict__ bqs,
                            float* __restrict__ biasf,
                            float* __restrict__ mkg) {
  const float SCQ = 0.17677669529663687f * LOG2E;
  const int stride = gridDim.x * blockDim.x;
  const int gid = blockIdx.x * blockDim.x + threadIdx.x;
  for (int e = gid; e < 48 * 8 * 64 * 8; e += stride) {
    int eL = e & 7, ln = (e >> 3) & 63, ks = (e >> 9) & 7, ctg = e >> 12;
    int k = ks * 32 + (ln >> 4) * 8 + eL;
    int c = ctg * 16 + (ln & 15);
    float wv = w_qkv[k * 768 + c];
    if (ctg < 16) wv *= SCQ;
    wqTf[e] = f2bf(wv);
  }
  for (int e = gid; e < 16 * 8 * 64 * 8; e += stride) {
    int eL = e & 7, ln = (e >> 3) & 63, ks = (e >> 9) & 7, ctg = e >> 12;
    int k = ks * 32 + (ln >> 4) * 8 + eL;
    int c = ctg * 16 + (ln & 15);
    woTf[e] = f2bf(w_out[k * 256 + c]);
  }
  for (int e = gid; e < 768; e += stride)
    bqs[e] = b_qkv[e] * (e < 256 ? SCQ : 1.f);
  for (int e = gid; e < 8 * 16 * 64 * 4; e += stride) {
    int rg = e & 3, ln = (e >> 2) & 63, t = (e >> 8) & 15, hh = e >> 12;
    int i = (t >> 2) * 16 + (ln & 15);
    int j = (t & 3) * 16 + (ln >> 4) * 4 + rg;
    float v;
    if (j >= NTOK) v = -1e30f;
    else if (i >= NTOK) v = 0.f;
    else {
      int dh = i / 7 - j / 7 + 6;
      int dw = i % 7 - j % 7 + 6;
      v = rel[(dh * 13 + dw) * 8 + hh];
    }
    biasf[e] = v * LOG2E;
  }
  for (int e = gid; e < 64 * 16 * 64 * 4; e += stride) {
    int rg = e & 3, ln = (e >> 2) & 63, t = (e >> 8) & 15, wdw = e >> 12;
    int i = (t >> 2) * 16 + (ln & 15);
    int j = (t & 3) * 16 + (ln >> 4) * 4 + rg;
    mkg[e] = (i < NTOK && j < NTOK) ? mask[wdw * (NTOK * NTOK) + i * NTOK + j] * LOG2E : 0.f;
  }
}

// ---------------- prep2: cmb = biasf + mkg (R14-verified) ----------------
__global__ void prep2_kernel(const float* __restrict__ biasf,
                             const float* __restrict__ mkg,
                             float* __restrict__ cmb) {
  const int stride = gridDim.x * blockDim.x;
  for (int e = blockIdx.x * blockDim.x + threadIdx.x; e < 64 * 8 * 4096; e += stride) {
    int x = e & 4095, hh = (e >> 12) & 7, wdw = e >> 15;
    cmb[e] = biasf[hh * 4096 + x] + mkg[wdw * 4096 + x];
  }
}

// ---------------- fused window attention: 16 waves, wave pair per head ----------------
__global__ void __launch_bounds__(1024, 4) winattn_mfma(
    const float* __restrict__ x,
    const float* __restrict__ bqs,
    const float* __restrict__ b_out,
    const u16* __restrict__ wqTf,
    const u16* __restrict__ woTf,
    const float* __restrict__ biasf,
    const float* __restrict__ mkg,
    const float* __restrict__ cmb,
    float* __restrict__ out)
{
  __shared__ u16 pool[POOLN];
  const int b = blockIdx.x, tid = threadIdx.x;
  const int lane = tid & 63, lo = lane & 15, hi = lane >> 4;
  const int w = tid >> 6;            // 0..15
  const int h = w & 7;               // head (attention phases)
  const int it0 = (w >> 3) * 2;      // i-tile half: 0 or 2
  const f32x4 zf = {0.f, 0.f, 0.f, 0.f};

  // ---- stage: x -> linear frag order ----
  {
    const float4* xg = (const float4*)(x + (size_t)b * (NTOK * 256));
    for (int e = tid; e < 49 * 64; e += 1024) {
      float4 v = xg[e];
      int r = e >> 6, c4 = (e & 63) << 2;
      int addr = (((r >> 4) * 8 + (c4 >> 5)) * 64 + ((c4 >> 3) & 3) * 16 + (r & 15)) * 8 + (c4 & 7);
      *(uint2*)&pool[XF + addr] = make_uint2(packbf(v.x, v.y), packbf(v.z, v.w));
    }
    if (tid < 15 * 64) {   // zero-pad tokens 49..63
      int e = tid;
      int r = 49 + (e >> 6), c4 = (e & 63) << 2;
      int addr = (((r >> 4) * 8 + (c4 >> 5)) * 64 + ((c4 >> 3) & 3) * 16 + (r & 15)) * 8 + (c4 & 7);
      *(uint2*)&pool[XF + addr] = make_uint2(0u, 0u);
    }
  }
  __syncthreads();   // (a) xf ready

  // ---- phase 1: QKV GEMM. wave w: q/k ctgs {2w,2w+1}; v ctg 32+w swapped-operand ----
  {
    const int ctq0 = 2 * w, ctq1 = 2 * w + 1, ctv = 32 + w;
    f32x4 acc[3][4];
    #pragma unroll
    for (int ct = 0; ct < 3; ++ct)
      #pragma unroll
      for (int rt = 0; rt < 4; ++rt) acc[ct][rt] = zf;
    #pragma unroll
    for (int ks = 0; ks < 8; ++ks) {
      short8 bx[4];
      #pragma unroll
      for (int rt = 0; rt < 4; ++rt)
        bx[rt] = *(const short8*)&pool[XF + ((rt * 8 + ks) * 64 + lane) * 8];
      short8 af0 = *(const short8*)&wqTf[((size_t)(ctq0 * 8 + ks) * 64 + lane) * 8];
      short8 af1 = *(const short8*)&wqTf[((size_t)(ctq1 * 8 + ks) * 64 + lane) * 8];
      short8 afv = *(const short8*)&wqTf[((size_t)(ctv * 8 + ks) * 64 + lane) * 8];
      #pragma unroll
      for (int rt = 0; rt < 4; ++rt) {
        acc[0][rt] = __builtin_amdgcn_mfma_f32_16x16x32_bf16(af0, bx[rt], acc[0][rt], 0, 0, 0);
        acc[1][rt] = __builtin_amdgcn_mfma_f32_16x16x32_bf16(af1, bx[rt], acc[1][rt], 0, 0, 0);
        acc[2][rt] = __builtin_amdgcn_mfma_f32_16x16x32_bf16(bx[rt], afv, acc[2][rt], 0, 0, 0);
      }
    }
    // epilogue q/k: wave w<8 -> q[head w]; w>=8 -> k[head w-8]
    const int qkbase = QKP + (w & 7) * 4096 + ((w >= 8) ? 2048 : 0);
    #pragma unroll
    for (int ct = 0; ct < 2; ++ct) {
      const int ctg = 2 * w + ct;
      f32x4 bias = *(const f32x4*)(bqs + ctg * 16 + hi * 4);
      #pragma unroll
      for (int rt = 0; rt < 4; ++rt) {
        f32x4 v = acc[ct][rt] + bias;
        int hi2 = ct * 2 + (hi >> 1);
        int eb = (hi & 1) * 4;
        *(uint2*)&pool[qkbase + (rt * 64 + hi2 * 16 + lo) * 8 + eb] =
            make_uint2(packbf(v[0], v[1]), packbf(v[2], v[3]));
      }
    }
    // epilogue v (swapped D: lane lo = channel, regs = tokens) -> packed b64
    {
      const int vhead = w >> 1, dblk = w & 1;
      const float bv = bqs[ctv * 16 + lo];
      #pragma unroll
      for (int rt = 0; rt < 4; ++rt) {
        f32x4 v = acc[2][rt];
        float v0 = v[0] + bv, v1 = v[1] + bv, v2 = v[2] + bv, v3 = v[3] + bv;
        int f = dblk * 2 + (rt >> 1);
        int hiR = (rt & 1) * 2 + (hi >> 1);
        int eb = (hi & 1) * 4;
        *(uint2*)&pool[VTF + (f * 8 + vhead) * 512 + (hiR * 16 + lo) * 8 + eb] =
            make_uint2(packbf(v0, v1), packbf(v2, v3));
      }
    }
  }
  __syncthreads();   // (b) q/k/v visible; XF dead (y may overwrite)

  // ---- va preload (both waves of a head read all 4 v slots) ----
  short8 va[2][2];
  #pragma unroll
  for (int dblk = 0; dblk < 2; ++dblk)
    #pragma unroll
    for (int k2 = 0; k2 < 2; ++k2)
      va[dblk][k2] = *(const short8*)&pool[VTF + ((dblk * 2 + k2) * 8 + h) * 512 + lane * 8];
  __syncthreads();   // (d) all va in regs -> VY slots become P scratch (2 per wave)

  // ---- phases 2-4 per i-tile: QK^T -> softmax -> P via dead VY -> PV -> y to XF ----
  {
    short8 qa[4], ka[2];
    #pragma unroll
    for (int jt = 0; jt < 4; ++jt)
      qa[jt] = *(const short8*)&pool[QKP + h * 4096 + (jt * 64 + lane) * 8];
    #pragma unroll
    for (int itL = 0; itL < 2; ++itL)
      ka[itL] = *(const short8*)&pool[QKP + h * 4096 + 2048 + ((it0 + itL) * 64 + lane) * 8];
    const float* cb;
    const float* mb = nullptr;
    if (cmb) {
      cb = cmb + (((size_t)(b & 63) * 8 + h) << 12);
    } else {
      cb = biasf + h * 4096;
      mb = mkg + (size_t)(b & 63) * 4096;
    }
    #pragma unroll
    for (int itL = 0; itL < 2; ++itL) {
      float rs = 0.f;
      #pragma unroll
      for (int jt = 0; jt < 4; ++jt) {
        f32x4 s = __builtin_amdgcn_mfma_f32_16x16x32_bf16(qa[jt], ka[itL], zf, 0, 0, 0);
        const int t = (it0 + itL) * 4 + jt;
        f32x4 c4 = *(const f32x4*)&cb[(t * 64 + lane) * 4];
        if (mb) {
          f32x4 m4 = *(const f32x4*)&mb[(t * 64 + lane) * 4];
          c4[0] += m4[0]; c4[1] += m4[1]; c4[2] += m4[2]; c4[3] += m4[3];
        }
        float p0 = exp2f(s[0] + c4[0]);
        float p1 = exp2f(s[1] + c4[1]);
        float p2 = exp2f(s[2] + c4[2]);
        float p3 = exp2f(s[3] + c4[3]);
        rs += (p0 + p1) + (p2 + p3);
        // P -> dead VY slot (R13-verified mapping): j = jt*16+hi*4+rg, i = lo
        int k2 = jt >> 1;
        int hi2 = (jt & 1) * 2 + (hi >> 1);
        int eb = (hi & 1) * 4;
        *(uint2*)&pool[VTF + ((it0 + k2) * 8 + h) * 512 + (hi2 * 16 + lo) * 8 + eb] =
            make_uint2(packbf(p0, p1), packbf(p2, p3));
      }
      float r2 = rs + __shfl_xor(rs, 16);
      const float inv = 1.f / (r2 + __shfl_xor(r2, 32));
      f32x4 ya0 = zf, ya1 = zf;
      #pragma unroll
      for (int k2 = 0; k2 < 2; ++k2) {
        short8 pb = *(const short8*)&pool[VTF + ((it0 + k2) * 8 + h) * 512 + lane * 8];
        ya0 = __builtin_amdgcn_mfma_f32_16x16x32_bf16(va[0][k2], pb, ya0, 0, 0, 0);
        ya1 = __builtin_amdgcn_mfma_f32_16x16x32_bf16(va[1][k2], pb, ya1, 0, 0, 0);
      }
      #pragma unroll
      for (int dblk = 0; dblk < 2; ++dblk) {
        f32x4 yy = dblk ? ya1 : ya0;
        int hi2 = dblk * 2 + (hi >> 1);
        int eb = (hi & 1) * 4;
        *(uint2*)&pool[XF + (((it0 + itL) * 8 + h) * 64 + hi2 * 16 + lo) * 8 + eb] =
            make_uint2(packbf(yy[0] * inv, yy[1] * inv), packbf(yy[2] * inv, yy[3] * inv));
      }
    }
  }
  __syncthreads();   // (c) y frags ready

  // ---- phase 5: output projection, 1 ctg per wave ----
  {
    f32x4 pacc[4];
    pacc[0] = zf; pacc[1] = zf; pacc[2] = zf; pacc[3] = zf;
    #pragma unroll
    for (int ks = 0; ks < 8; ++ks) {
      short8 wf = *(const short8*)&woTf[((size_t)(w * 8 + ks) * 64 + lane) * 8];
      #pragma unroll
      for (int rt = 0; rt < 4; ++rt) {
        short8 yb = *(const short8*)&pool[XF + ((rt * 8 + ks) * 64 + lane) * 8];
        pacc[rt] = __builtin_amdgcn_mfma_f32_16x16x32_bf16(wf, yb, pacc[rt], 0, 0, 0);
      }
    }
    float* og = out + (size_t)b * (NTOK * 256);
    const int cb2 = w * 16 + hi * 4;
    f32x4 bb = *(const f32x4*)(b_out + cb2);
    #pragma unroll
    for (int rt = 0; rt < 4; ++rt) {
      const int r = rt * 16 + lo;
      if (r < NTOK) {
        f32x4 vv = pacc[rt] + bb;
        *(f32x4*)(og + (size_t)r * 256 + cb2) = vv;
      }
    }
  }
}

extern "C" void kernel_launch(void* const* d_in, const int* in_sizes, int n_in,
                              void* d_out, int out_size, void* d_ws, size_t ws_size,
                              hipStream_t stream) {
  const float *x = nullptr, *mask = nullptr, *w_qkv = nullptr, *b_qkv = nullptr,
              *rel_t = nullptr, *w_out = nullptr, *b_out = nullptr;
  for (int i = 0; i < n_in; ++i) {
    const float* p = (const float*)d_in[i];
    switch (in_sizes[i]) {
      case 4096 * 49 * 256: x = p; break;
      case 64 * 49 * 49:    mask = p; break;
      case 256 * 768:       w_qkv = p; break;
      case 768:             b_qkv = p; break;
      case 169 * 8:         rel_t = p; break;
      case 256 * 256:       w_out = p; break;
      case 256:             b_out = p; break;
    }
  }
  char* wsb = (char*)d_ws;
  u16* wqTf    = (u16*)(wsb + WS_WQT);
  u16* woTf    = (u16*)(wsb + WS_WOT);
  float* bqs   = (float*)(wsb + WS_BQS);
  float* biasf = (float*)(wsb + WS_BIAS);
  float* mkg   = (float*)(wsb + WS_MKG);
  const bool fits = (ws_size >= (size_t)WS_NEED);
  float* cmb   = fits ? (float*)(wsb + WS_CMB) : nullptr;

  hipLaunchKernelGGL(prep_kernel, dim3(1024), dim3(256), 0, stream,
                     w_qkv, w_out, rel_t, mask, b_qkv, wqTf, woTf, bqs, biasf, mkg);
  if (fits) {
    hipLaunchKernelGGL(prep2_kernel, dim3(2048), dim3(256), 0, stream,
                       biasf, mkg, cmb);
  }
  hipLaunchKernelGGL(winattn_mfma, dim3(NBLK), dim3(1024), 0, stream,
                     x, bqs, b_out, wqTf, woTf, biasf, mkg, cmb, (float*)d_out);
}